// Round 4
// baseline (200.302 us; speedup 1.0000x reference)
//
#include <hip/hip_runtime.h>
#include <hip/hip_bf16.h>
#include <stdint.h>

// Flash-attention (causal, GQA) B=4, S=1024, HQ=32, HK=8, D=128, fp32 io.
// R4: 32x32x16 MFMAs, S^T orientation, kappa-permuted K so P exits softmax
// in PV A-operand layout. R5: balanced pair-blocks (p,7-p), 18 tiles each.
// R6: XCD-grouped mapping (bx&7=hk), LDS dbuf, defer-rescale, setprio.
// R7: bf16 prep-pass + global_load_lds DMA staging.
// R8: LDS-pipe attack. rocprof r3: per-CU tile-step ~5k cyc; LDS reads =
//   256 KB/CU-step (8 waves x 32 b128) ~2.3k cyc + conflicts 4.46M (x2 of
//   r2: 256B-row K image + 4-way V granule swizzle) -> LDS is the top pipe.
//   Changes:
//   (1) K never touches LDS: prep emits K frag-ordered (region (c,dM) =
//       1KB = [half][slot][16B] = lane*16), main kernel loads A-frags with
//       coalesced global_load_dwordx4 straight to VGPRs; the 4-wave
//       redundancy is served by L1 (16KB tile), not LDS.
//   (2) V swizzle g^((d>>1)&7) on BOTH prep-write and read: 2 lanes/slot
//       in each 16-lane phase = conflict-free (m136: 2-way is free).
//   (3) DMA is V-only (16 KB/tile), LDS 33 KB.
//   (4) exp2 domain: log2e folded into Q scale; P=exp2(s-m), al=exp2(dm).
//
// Layout facts (m74/m101-verified): 32x32 C/D: col=lane&31,
// row=(reg&3)+8*(reg>>2)+4*(lane>>5). A: m=lane&31, k=(lane>>5)*8+j.
// B: n=lane&31, k=(lane>>5)*8+j.
// kappa: key kk sits at slot mu = (kk&3)+4*((kk>>3)&1)+8*(2*((kk>>4)&1)
// +((kk>>2)&1)) (per 32-key chunk) => P regs [8c..8c+7] are PV A-frags.

typedef __bf16 v8bf __attribute__((ext_vector_type(8)));
typedef __bf16 v4bf __attribute__((ext_vector_type(4)));
typedef float  v16f __attribute__((ext_vector_type(16)));

#define NB  4
#define NS  1024
#define NHQ 32
#define NHK 8
#define ND  128
#define BQ  128
#define BK  64
#define VOFF (8u << 20)   // V image base in ws (K = 8 MB, V = 8 MB)

#define KOFF(r) (16*((r)>>3) + ((((r)>>2)&1)*4) + ((r)&3))

// ---------------- pre-pass: fp32 K/V -> bf16 tile images ------------------
// Per (b,hk,t) tile (t = 64-key tile): K image 16 KB at tileid*16384:
//   16 regions f=(c*8+dM) of 1 KB: byte = f*1024 + half*512 + mu*16 + j*2
//   (mu = kappa slot of key within 32-chunk c; d = dM*16+half*8+j).
// V image 16 KB at VOFF + tileid*16384: byte = d*128 + (g^((d>>1)&7))*16,
//   granule g = 8 keys, elements = keys 8g..8g+7 along the 16 B.
__global__ __launch_bounds__(256)
void prep(const float* __restrict__ kg, const float* __restrict__ vg,
          char* __restrict__ ws)
{
  const int tid = threadIdx.x;
  const int blk = blockIdx.x;
  if (blk < 4096) {                 // ---- K: 1M threads, float4 -> 8B write
    int gid = blk * 256 + tid;
    int i  = gid & 31;              // d-quad, d = 4i..4i+3
    int s  = (gid >> 5) & (NS - 1); // key within (b,hk)
    int hk = (gid >> 15) & 7;
    int b  = gid >> 18;
    float4 f = *(const float4*)(kg + ((size_t)((b * NS + s) * NHK + hk)) * ND + 4 * i);
    v4bf kb;
    kb[0]=(__bf16)f.x; kb[1]=(__bf16)f.y; kb[2]=(__bf16)f.z; kb[3]=(__bf16)f.w;
    int t  = s >> 6;
    int c  = (s >> 5) & 1;
    int kk = s & 31;
    int mu = (kk & 3) + 4 * ((kk >> 3) & 1)
           + 8 * (2 * ((kk >> 4) & 1) + ((kk >> 2) & 1));
    int fidx  = c * 8 + (i >> 2);        // dM = i>>2
    int halfb = (i >> 1) & 1;
    int byte  = fidx * 1024 + halfb * 512 + mu * 16 + ((4 * i) & 7) * 2;
    size_t tb = (size_t)((b * 8 + hk) * 16 + t) << 14;
    *(v4bf*)(ws + tb + byte) = kb;
  } else {                          // ---- V: 0.5M threads, 8 gathers -> 16B
    int vid = (blk - 4096) * 256 + tid;
    int d  = vid & 127;
    int g  = (vid >> 7) & 7;        // granule = 8 keys
    int t  = (vid >> 10) & 15;
    int hk = (vid >> 14) & 7;
    int b  = vid >> 17;
    const float* vp = vg + ((size_t)((b * NS + t * 64 + g * 8) * NHK + hk)) * ND + d;
    v8bf w;
    #pragma unroll
    for (int e = 0; e < 8; ++e) w[e] = (__bf16)vp[(size_t)e * (NHK * ND)];
    int byte = (d * 8 + (g ^ ((d >> 1) & 7))) * 16;
    size_t tb = (size_t)((b * 8 + hk) * 16 + t) << 14;
    *(v8bf*)(ws + VOFF + tb + byte) = w;
  }
}

// ---------------- main kernel --------------------------------------------
__global__ __launch_bounds__(256, 2)
void fattn(const float* __restrict__ qg, const char* __restrict__ kvg,
           float* __restrict__ og)
{
  __shared__ __align__(16) char  Vt[2][16384];  // V tile image x dbuf
  __shared__ __align__(16) float alq[4 * 32];   // per-wave alpha / inv-l

  const int tid  = threadIdx.x;
  const int lane = tid & 63;
  const int wave = tid >> 6;
  const int half = lane >> 5;
  const int l31  = lane & 31;

  // XCD-grouped decode: bx = ((b*16 + p*4 + c) << 3) | hk
  const int bx = blockIdx.x;
  const int hk = bx & 7;
  const int t6 = bx >> 3;
  const int b  = t6 >> 4;
  const int m6 = t6 & 15;
  const int p  = m6 >> 2;                // q-tile pair id: tiles (p, 7-p)
  const int h  = hk * 4 + (m6 & 3);

  // 1/sqrt(128) * log2(e): softmax runs in exp2 domain
  const float scale = 0.12751879523604785f;
  const int kvtile = (b * 8 + hk) * 16;  // ws tile-id base

  // DMA one 16 KB V tile: 16 chunks of 1 KB; wave w takes chunks 4w..4w+3.
  auto dmaV = [&](int t_, char* dst) {
    const char* src = kvg + VOFF + ((size_t)(kvtile + t_) << 14);
    #pragma unroll
    for (int i = 0; i < 4; ++i) {
      int c = wave * 4 + i;
      __builtin_amdgcn_global_load_lds(
        (const __attribute__((address_space(1))) void*)(src + c * 1024 + lane * 16),
        (__attribute__((address_space(3))) void*)(dst + c * 1024),
        16, 0, 0);
    }
  };

  dmaV(0, Vt[0]);
  int cur = 0;

  for (int ph = 0; ph < 2; ++ph) {
    const int qt = ph ? (7 - p) : p;
    const int wv = ph ? (3 - wave) : wave;   // reverse rows in phase B
    const int q0 = qt * BQ;
    const int wqb = q0 + wv * 32;
    const int qglob = wqb + l31;
    const int ntiles = 2 * (qt + 1);

    // Q fragments (B-operand: n=q=l31, k=d=dM*16+half*8+j), scale folded
    v8bf qf[8];
    {
      const float* qp = qg + ((size_t)((b * NS + qglob) * NHQ + h)) * ND + half * 8;
      #pragma unroll
      for (int dM = 0; dM < 8; ++dM) {
        float4 f0 = *(const float4*)(qp + dM * 16);
        float4 f1 = *(const float4*)(qp + dM * 16 + 4);
        v8bf t;
        t[0]=(__bf16)(f0.x*scale); t[1]=(__bf16)(f0.y*scale);
        t[2]=(__bf16)(f0.z*scale); t[3]=(__bf16)(f0.w*scale);
        t[4]=(__bf16)(f1.x*scale); t[5]=(__bf16)(f1.y*scale);
        t[6]=(__bf16)(f1.z*scale); t[7]=(__bf16)(f1.w*scale);
        qf[dM] = t;
      }
    }

    v16f accO[4];
    #pragma unroll
    for (int dt = 0; dt < 4; ++dt)
      #pragma unroll
      for (int e = 0; e < 16; ++e) accO[dt][e] = 0.f;
    float m_run = -INFINITY, l_run = 0.f;

    for (int t = 0; t < ntiles; ++t) {
      const int k0 = t * BK;

      // my V-DMA into Vt[cur] landed; all waves done reading Vt[cur^1]
      asm volatile("s_waitcnt vmcnt(0)" ::: "memory");
      __syncthreads();

      // issue next tile's V-DMA into the free buffer (lands during compute)
      if (t + 1 < ntiles)      dmaV(t + 1, Vt[cur ^ 1]);
      else if (ph == 0)        dmaV(0, Vt[cur ^ 1]);

      if (k0 <= wqb + 31) {
        // --- K A-frags straight from global (frag-ordered image, L1-hot):
        // region f=(c*8+dM) is 1 KB = lane*16 -> coalesced dwordx4 ---
        const v8bf* kf = (const v8bf*)(kvg + ((size_t)(kvtile + t) << 14) + lane * 16);
        v8bf ka0[8], ka1[8];
        #pragma unroll
        for (int f = 0; f < 8; ++f) ka0[f] = kf[(size_t)f * 64];
        #pragma unroll
        for (int f = 0; f < 8; ++f) ka1[f] = kf[(size_t)(f + 8) * 64];

        v16f s0, s1;
        #pragma unroll
        for (int e = 0; e < 16; ++e) { s0[e] = 0.f; s1[e] = 0.f; }
        __builtin_amdgcn_s_setprio(1);
        #pragma unroll
        for (int dM = 0; dM < 8; ++dM)
          s0 = __builtin_amdgcn_mfma_f32_32x32x16_bf16(ka0[dM], qf[dM], s0, 0, 0, 0);
        #pragma unroll
        for (int dM = 0; dM < 8; ++dM)
          s1 = __builtin_amdgcn_mfma_f32_32x32x16_bf16(ka1[dM], qf[dM], s1, 0, 0, 0);
        __builtin_amdgcn_s_setprio(0);
        // --- causal mask (diagonal region only) ---
        if (k0 + BK > wqb) {
          #pragma unroll
          for (int r = 0; r < 16; ++r) {
            int key = k0 + KOFF(r) + half * 8;
            if (key > qglob)      s0[r] = -INFINITY;
            if (key + 32 > qglob) s1[r] = -INFINITY;
          }
        }
        // --- online softmax in exp2 domain ---
        float m0 = s0[0];
        #pragma unroll
        for (int r = 1; r < 16; ++r) m0 = fmaxf(m0, s0[r]);
        #pragma unroll
        for (int r = 0; r < 16; ++r) m0 = fmaxf(m0, s1[r]);
        m0 = fmaxf(m0, __shfl_xor(m0, 32));
        float mn = fmaxf(m_run, m0);
        float rs = 0.f;
        #pragma unroll
        for (int r = 0; r < 16; ++r) { float pp = exp2f(s0[r] - mn); s0[r] = pp; rs += pp; }
        #pragma unroll
        for (int r = 0; r < 16; ++r) { float pp = exp2f(s1[r] - mn); s1[r] = pp; rs += pp; }
        rs += __shfl_xor(rs, 32);
        // --- defer-rescale: alpha==1 for every lane -> skip (exact) ---
        if (__any(m0 > m_run)) {
          float al = exp2f(m_run - mn);
          if (half == 0) alq[wave * 32 + l31] = al;
          float4 alf[4];
          #pragma unroll
          for (int c = 0; c < 4; ++c)
            alf[c] = *(const float4*)(&alq[wave * 32 + 8 * c + 4 * half]);
          #pragma unroll
          for (int dt = 0; dt < 4; ++dt)
            #pragma unroll
            for (int r = 0; r < 16; ++r)
              accO[dt][r] *= ((const float*)&alf[r >> 2])[r & 3];
          l_run = l_run * al + rs;
        } else {
          l_run += rs;
        }
        m_run = mn;
        // --- O += P V : A = P (in regs, kappa-aligned), B = V image ---
        const char* vtr = Vt[cur];
        __builtin_amdgcn_s_setprio(1);
        #pragma unroll
        for (int C = 0; C < 2; ++C) {
          #pragma unroll
          for (int cp = 0; cp < 2; ++cp) {
            v8bf pf;
            #pragma unroll
            for (int e = 0; e < 8; ++e)
              pf[e] = (__bf16)(C == 0 ? s0[cp * 8 + e] : s1[cp * 8 + e]);
            int g = (C * 2 + cp) * 2 + half;
            #pragma unroll
            for (int dt = 0; dt < 4; ++dt) {
              int d = dt * 32 + l31;
              v8bf vb = *(const v8bf*)(vtr + (d * 8 + (g ^ ((l31 >> 1) & 7))) * 16);
              accO[dt] = __builtin_amdgcn_mfma_f32_32x32x16_bf16(pf, vb, accO[dt], 0, 0, 0);
            }
          }
        }
        __builtin_amdgcn_s_setprio(0);
      }
      cur ^= 1;
    }

    // --- epilogue: O / l, fp32 stores ---
    if (half == 0) alq[wave * 32 + l31] = 1.f / l_run;
    float4 invf[4];
    #pragma unroll
    for (int c = 0; c < 4; ++c)
      invf[c] = *(const float4*)(&alq[wave * 32 + 8 * c + 4 * half]);
    #pragma unroll
    for (int dt = 0; dt < 4; ++dt) {
      #pragma unroll
      for (int r = 0; r < 16; ++r) {
        int qrow = (r & 3) + 8 * (r >> 2) + 4 * half;
        float* op = og + ((size_t)((b * NS + wqb + qrow) * NHQ + h)) * ND;
        op[dt * 32 + l31] = accO[dt][r] * ((const float*)&invf[r >> 2])[r & 3];
      }
    }
  }
}

extern "C" void kernel_launch(void* const* d_in, const int* in_sizes, int n_in,
                              void* d_out, int out_size, void* d_ws, size_t ws_size,
                              hipStream_t stream) {
  const float* q = (const float*)d_in[0];
  const float* k = (const float*)d_in[1];
  const float* v = (const float*)d_in[2];
  float* out = (float*)d_out;
  char* ws = (char*)d_ws;   // 16 MiB: 512 tiles x (16 KB K image + 16 KB V image)
  prep<<<dim3(4096 + 2048), 256, 0, stream>>>(k, v, ws);
  fattn<<<dim3(NB * NHQ * 4), 256, 0, stream>>>(q, ws, out);
}

// Round 5
// 199.469 us; speedup vs baseline: 1.0042x; 1.0042x over previous
//
#include <hip/hip_runtime.h>
#include <hip/hip_bf16.h>
#include <stdint.h>

// Flash-attention (causal, GQA) B=4, S=1024, HQ=32, HK=8, D=128, fp32 io.
// R4: 32x32x16 MFMAs, S^T orientation, kappa-permuted K so P exits softmax
// in PV A-operand layout. R5: balanced pair-blocks (p,7-p), 18 tiles each.
// R6: XCD-grouped mapping (bx&7=hk), LDS dbuf, defer-rescale, setprio.
// R7: bf16 prep-pass + global_load_lds DMA staging (75us, conflicts 4.46M).
// R8: K from global frag-image (conflicts 0) -- REGRESSED to 89us: K fetch
//   moved onto the critical path (issued right before consuming MFMAs,
//   ~950 cyc/step exposed L1/L2 latency; R7 had it landing a full compute
//   phase ahead via DMA).
// R9: best of both. K returns to LDS via DMA (prefetch distance 1 tile),
//   but keeps R8's FRAG-ORDERED image: region f=(c*8+dM) is 1 KB laid out
//   as lane*16, so it (a) DMAs linearly with global_load_lds and (b) reads
//   back as ds_read_b128 at f*1024+lane*16 -- a contiguous 1KB wave-read,
//   ~2 lanes/bank = conflict-free (m136), unlike R7's 256B-strided rows.
//   V keeps R8's g^((d>>1)&7) image (measured 0 conflicts). Compute phase
//   touches only LDS; all global traffic is 1-tile-ahead DMA.
//
// Layout facts (m74/m101-verified): 32x32 C/D: col=lane&31,
// row=(reg&3)+8*(reg>>2)+4*(lane>>5). A: m=lane&31, k=(lane>>5)*8+j.
// B: n=lane&31, k=(lane>>5)*8+j.
// kappa: key kk sits at slot mu = (kk&3)+4*((kk>>3)&1)+8*(2*((kk>>4)&1)
// +((kk>>2)&1)) (per 32-key chunk) => P regs [8c..8c+7] are PV A-frags.

typedef __bf16 v8bf __attribute__((ext_vector_type(8)));
typedef __bf16 v4bf __attribute__((ext_vector_type(4)));
typedef float  v16f __attribute__((ext_vector_type(16)));

#define NB  4
#define NS  1024
#define NHQ 32
#define NHK 8
#define ND  128
#define BQ  128
#define BK  64

#define KOFF(r) (16*((r)>>3) + ((((r)>>2)&1)*4) + ((r)&3))

// ---------------- pre-pass: fp32 K/V -> bf16 tile images ------------------
// Per (b,hk,t) tile (t = 64-key tile), 32 KB at tileid<<15:
//  K image [0,16K): 16 regions f=(c*8+dM) of 1 KB:
//    byte = f*1024 + half*512 + mu*16 + j*2  (d = dM*16+half*8+j, mu=kappa)
//  V image [16K,32K): byte = d*128 + (g^((d>>1)&7))*16, granule g = 8 keys.
__global__ __launch_bounds__(256)
void prep(const float* __restrict__ kg, const float* __restrict__ vg,
          char* __restrict__ ws)
{
  const int tid = threadIdx.x;
  const int blk = blockIdx.x;
  if (blk < 4096) {                 // ---- K: 1M threads, float4 -> 8B write
    int gid = blk * 256 + tid;
    int i  = gid & 31;              // d-quad, d = 4i..4i+3
    int s  = (gid >> 5) & (NS - 1); // key within (b,hk)
    int hk = (gid >> 15) & 7;
    int b  = gid >> 18;
    float4 f = *(const float4*)(kg + ((size_t)((b * NS + s) * NHK + hk)) * ND + 4 * i);
    v4bf kb;
    kb[0]=(__bf16)f.x; kb[1]=(__bf16)f.y; kb[2]=(__bf16)f.z; kb[3]=(__bf16)f.w;
    int t  = s >> 6;
    int c  = (s >> 5) & 1;
    int kk = s & 31;
    int mu = (kk & 3) + 4 * ((kk >> 3) & 1)
           + 8 * (2 * ((kk >> 4) & 1) + ((kk >> 2) & 1));
    int fidx  = c * 8 + (i >> 2);        // dM = i>>2
    int halfb = (i >> 1) & 1;
    int byte  = fidx * 1024 + halfb * 512 + mu * 16 + ((4 * i) & 7) * 2;
    size_t tb = (size_t)((b * 8 + hk) * 16 + t) << 15;
    *(v4bf*)(ws + tb + byte) = kb;
  } else {                          // ---- V: 0.5M threads, 8 gathers -> 16B
    int vid = (blk - 4096) * 256 + tid;
    int d  = vid & 127;
    int g  = (vid >> 7) & 7;        // granule = 8 keys
    int t  = (vid >> 10) & 15;
    int hk = (vid >> 14) & 7;
    int b  = vid >> 17;
    const float* vp = vg + ((size_t)((b * NS + t * 64 + g * 8) * NHK + hk)) * ND + d;
    v8bf w;
    #pragma unroll
    for (int e = 0; e < 8; ++e) w[e] = (__bf16)vp[(size_t)e * (NHK * ND)];
    int byte = (d * 8 + (g ^ ((d >> 1) & 7))) * 16;
    size_t tb = (size_t)((b * 8 + hk) * 16 + t) << 15;
    *(v8bf*)(ws + tb + 16384 + byte) = w;
  }
}

// ---------------- main kernel --------------------------------------------
__global__ __launch_bounds__(256, 2)
void fattn(const float* __restrict__ qg, const char* __restrict__ kvg,
           float* __restrict__ og)
{
  __shared__ __align__(16) char  KV[2][32768];  // [K 16K | V 16K] x dbuf
  __shared__ __align__(16) float alq[4 * 32];   // per-wave alpha / inv-l

  const int tid  = threadIdx.x;
  const int lane = tid & 63;
  const int wave = tid >> 6;
  const int half = lane >> 5;
  const int l31  = lane & 31;

  // XCD-grouped decode: bx = ((b*16 + p*4 + c) << 3) | hk
  const int bx = blockIdx.x;
  const int hk = bx & 7;
  const int t6 = bx >> 3;
  const int b  = t6 >> 4;
  const int m6 = t6 & 15;
  const int p  = m6 >> 2;                // q-tile pair id: tiles (p, 7-p)
  const int h  = hk * 4 + (m6 & 3);

  // 1/sqrt(128) * log2(e): softmax runs in exp2 domain
  const float scale = 0.12751879523604785f;
  const int kvtile = (b * 8 + hk) * 16;  // ws tile-id base

  // DMA one 32 KB K/V tile: 32 chunks of 1 KB; wave w takes chunks 8w..8w+7.
  auto dma = [&](int t_, char* dst) {
    const char* src = kvg + ((size_t)(kvtile + t_) << 15);
    #pragma unroll
    for (int i = 0; i < 8; ++i) {
      int c = wave * 8 + i;
      __builtin_amdgcn_global_load_lds(
        (const __attribute__((address_space(1))) void*)(src + c * 1024 + lane * 16),
        (__attribute__((address_space(3))) void*)(dst + c * 1024),
        16, 0, 0);
    }
  };

  dma(0, KV[0]);
  int cur = 0;

  for (int ph = 0; ph < 2; ++ph) {
    const int qt = ph ? (7 - p) : p;
    const int wv = ph ? (3 - wave) : wave;   // reverse rows in phase B
    const int q0 = qt * BQ;
    const int wqb = q0 + wv * 32;
    const int qglob = wqb + l31;
    const int ntiles = 2 * (qt + 1);

    // Q fragments (B-operand: n=q=l31, k=d=dM*16+half*8+j), scale folded
    v8bf qf[8];
    {
      const float* qp = qg + ((size_t)((b * NS + qglob) * NHQ + h)) * ND + half * 8;
      #pragma unroll
      for (int dM = 0; dM < 8; ++dM) {
        float4 f0 = *(const float4*)(qp + dM * 16);
        float4 f1 = *(const float4*)(qp + dM * 16 + 4);
        v8bf t;
        t[0]=(__bf16)(f0.x*scale); t[1]=(__bf16)(f0.y*scale);
        t[2]=(__bf16)(f0.z*scale); t[3]=(__bf16)(f0.w*scale);
        t[4]=(__bf16)(f1.x*scale); t[5]=(__bf16)(f1.y*scale);
        t[6]=(__bf16)(f1.z*scale); t[7]=(__bf16)(f1.w*scale);
        qf[dM] = t;
      }
    }

    v16f accO[4];
    #pragma unroll
    for (int dt = 0; dt < 4; ++dt)
      #pragma unroll
      for (int e = 0; e < 16; ++e) accO[dt][e] = 0.f;
    float m_run = -INFINITY, l_run = 0.f;

    for (int t = 0; t < ntiles; ++t) {
      const int k0 = t * BK;

      // my DMA into KV[cur] landed; all waves done reading KV[cur^1]
      asm volatile("s_waitcnt vmcnt(0)" ::: "memory");
      __syncthreads();

      // issue next tile's DMA into the free buffer (lands during compute)
      if (t + 1 < ntiles)      dma(t + 1, KV[cur ^ 1]);
      else if (ph == 0)        dma(0, KV[cur ^ 1]);

      if (k0 <= wqb + 31) {
        const char* ksr = KV[cur];
        const char* vtr = KV[cur] + 16384;
        // --- K A-frags from LDS: region f is contiguous 1KB = lane*16 ---
        v8bf ka0[8], ka1[8];
        #pragma unroll
        for (int f = 0; f < 8; ++f)
          ka0[f] = *(const v8bf*)(ksr + f * 1024 + lane * 16);
        #pragma unroll
        for (int f = 0; f < 8; ++f)
          ka1[f] = *(const v8bf*)(ksr + (f + 8) * 1024 + lane * 16);

        v16f s0, s1;
        #pragma unroll
        for (int e = 0; e < 16; ++e) { s0[e] = 0.f; s1[e] = 0.f; }
        __builtin_amdgcn_s_setprio(1);
        #pragma unroll
        for (int dM = 0; dM < 8; ++dM)
          s0 = __builtin_amdgcn_mfma_f32_32x32x16_bf16(ka0[dM], qf[dM], s0, 0, 0, 0);
        #pragma unroll
        for (int dM = 0; dM < 8; ++dM)
          s1 = __builtin_amdgcn_mfma_f32_32x32x16_bf16(ka1[dM], qf[dM], s1, 0, 0, 0);
        __builtin_amdgcn_s_setprio(0);
        // --- causal mask (diagonal region only) ---
        if (k0 + BK > wqb) {
          #pragma unroll
          for (int r = 0; r < 16; ++r) {
            int key = k0 + KOFF(r) + half * 8;
            if (key > qglob)      s0[r] = -INFINITY;
            if (key + 32 > qglob) s1[r] = -INFINITY;
          }
        }
        // --- online softmax in exp2 domain ---
        float m0 = s0[0];
        #pragma unroll
        for (int r = 1; r < 16; ++r) m0 = fmaxf(m0, s0[r]);
        #pragma unroll
        for (int r = 0; r < 16; ++r) m0 = fmaxf(m0, s1[r]);
        m0 = fmaxf(m0, __shfl_xor(m0, 32));
        float mn = fmaxf(m_run, m0);
        float rs = 0.f;
        #pragma unroll
        for (int r = 0; r < 16; ++r) { float pp = exp2f(s0[r] - mn); s0[r] = pp; rs += pp; }
        #pragma unroll
        for (int r = 0; r < 16; ++r) { float pp = exp2f(s1[r] - mn); s1[r] = pp; rs += pp; }
        rs += __shfl_xor(rs, 32);
        // --- defer-rescale: alpha==1 for every lane -> skip (exact) ---
        if (__any(m0 > m_run)) {
          float al = exp2f(m_run - mn);
          if (half == 0) alq[wave * 32 + l31] = al;
          float4 alf[4];
          #pragma unroll
          for (int c = 0; c < 4; ++c)
            alf[c] = *(const float4*)(&alq[wave * 32 + 8 * c + 4 * half]);
          #pragma unroll
          for (int dt = 0; dt < 4; ++dt)
            #pragma unroll
            for (int r = 0; r < 16; ++r)
              accO[dt][r] *= ((const float*)&alf[r >> 2])[r & 3];
          l_run = l_run * al + rs;
        } else {
          l_run += rs;
        }
        m_run = mn;
        // --- O += P V : A = P (in regs, kappa-aligned), B = V image ---
        __builtin_amdgcn_s_setprio(1);
        #pragma unroll
        for (int C = 0; C < 2; ++C) {
          #pragma unroll
          for (int cp = 0; cp < 2; ++cp) {
            v8bf pf;
            #pragma unroll
            for (int e = 0; e < 8; ++e)
              pf[e] = (__bf16)(C == 0 ? s0[cp * 8 + e] : s1[cp * 8 + e]);
            int g = (C * 2 + cp) * 2 + half;
            #pragma unroll
            for (int dt = 0; dt < 4; ++dt) {
              int d = dt * 32 + l31;
              v8bf vb = *(const v8bf*)(vtr + (d * 8 + (g ^ ((l31 >> 1) & 7))) * 16);
              accO[dt] = __builtin_amdgcn_mfma_f32_32x32x16_bf16(pf, vb, accO[dt], 0, 0, 0);
            }
          }
        }
        __builtin_amdgcn_s_setprio(0);
      }
      cur ^= 1;
    }

    // --- epilogue: O / l, fp32 stores ---
    if (half == 0) alq[wave * 32 + l31] = 1.f / l_run;
    float4 invf[4];
    #pragma unroll
    for (int c = 0; c < 4; ++c)
      invf[c] = *(const float4*)(&alq[wave * 32 + 8 * c + 4 * half]);
    #pragma unroll
    for (int dt = 0; dt < 4; ++dt) {
      #pragma unroll
      for (int r = 0; r < 16; ++r) {
        int qrow = (r & 3) + 8 * (r >> 2) + 4 * half;
        float* op = og + ((size_t)((b * NS + wqb + qrow) * NHQ + h)) * ND;
        op[dt * 32 + l31] = accO[dt][r] * ((const float*)&invf[r >> 2])[r & 3];
      }
    }
  }
}

extern "C" void kernel_launch(void* const* d_in, const int* in_sizes, int n_in,
                              void* d_out, int out_size, void* d_ws, size_t ws_size,
                              hipStream_t stream) {
  const float* q = (const float*)d_in[0];
  const float* k = (const float*)d_in[1];
  const float* v = (const float*)d_in[2];
  float* out = (float*)d_out;
  char* ws = (char*)d_ws;   // 16 MiB: 512 tiles x 32 KB (frag-ordered K | V)
  prep<<<dim3(4096 + 2048), 256, 0, stream>>>(k, v, ws);
  fattn<<<dim3(NB * NHQ * 4), 256, 0, stream>>>(q, ws, out);
}